// Round 10
// baseline (920.925 us; speedup 1.0000x reference)
//
#include <hip/hip_runtime.h>
#include <hip/hip_bf16.h>

// Problem: B=8192 rows, D=4096. 3 layers of relu(l2norm(h) @ W^T + b).
// GEMM: 256x256 tile, BK=64, 8 waves, 16x16x32 MFMA, 2 phases/K-tile.
// ROUND 10 = R6 structure + counted vmcnt via STATIC A-triple-buffer.
// R9's counted-vmcnt attempt regressed because runtime 5-pointer rotation
// added VALU (18.3->22.8%) and killed imm-offset folding. Here the t-loop
// is unrolled with period LCM(3,2)=6 (NT=64: 10x6 + 4 tail bodies) so all
// LDS slot bases are compile-time constants. LDS 160 KiB: A slots 0..2,
// B bufs 3..4.
//
// Per tile t (A slot s=t%3, B parity p=t%2):
//  ph0: read bF(t) x8 [pre-BAR] | BAR | stage A(t+2)->slot (t+2)%3 |
//       GATE [bF + aX(t)] | window aY(t) x8 | MFMA16(acc[0..3], aX)
//  ph1: VMW(4) | BAR | GATE [aY] | stage B(t+2)->buf p |
//       window aX(t+1) x8 <- slot (t+1)%3 | MFMA16(acc[4..7], aY)
// FIFO ledger (induction): after ph1(t)'s wait, in-flight = [A(t+2)x4].
//  += B(t+2) (ph1 t), += A(t+3) (ph0 t+1) -> at ph1(t+1): 12 outstanding,
//  VMW(4) retires A(t+2) (1.5 tiles old) + B(t+2) (1 tile) exactly. Base:
//  prologue VMW(0) -> tile0 ph1 queue=[A(2)]=4, VMW(4) no-op. Tail t>=62:
//  VMW(0) (stages skipped). Per-wave vmcnt + following BARRIER => data
//  staged by ALL waves is landed before any post-BAR read.
// WAR (stage after a barrier following victims' readers' lgkm0):
//  A(t+2)->slot(t-1)%3 @ph0(t) post-BAR: aX(t-1) gated ph0(t-1) GATE,
//  aY(t-1) gated ph1(t-1) GATE, both < BAR(ph0 t). B(t+2)->buf p
//  (overwrites B(t)) @ph1(t) post-BAR: bF(t) gated ph0(t) GATE < BAR.
// RAW: bF(t)/aY(t)/aX(t) reads all follow the VMW that retires their
//  operand + a BARRIER. Prologue VMW(0) is order-independent (R7 lesson).

#define NROWS 8192
#define DIM   4096

typedef __bf16 bf16x8 __attribute__((ext_vector_type(8)));
typedef float  f32x4  __attribute__((ext_vector_type(4)));

__device__ static inline short f2bf(float f) {
  __hip_bfloat16 h = __float2bfloat16(f);
  return __builtin_bit_cast(short, h);
}

#define BARRIER() do { asm volatile("" ::: "memory"); \
                       __builtin_amdgcn_s_barrier();  \
                       asm volatile("" ::: "memory"); } while (0)
#define GATE()   do { asm volatile("s_waitcnt lgkmcnt(0)" ::: "memory"); \
                      __builtin_amdgcn_sched_barrier(0); } while (0)
#define VMW(N)   do { asm volatile("s_waitcnt vmcnt(" #N ")" ::: "memory"); \
                      __builtin_amdgcn_sched_barrier(0); } while (0)

__global__ __launch_bounds__(512, 2)
void gemm256_bias_relu(const short* __restrict__ A,
                       const short* __restrict__ Bw,
                       const float* __restrict__ bias,
                       float* __restrict__ C,
                       int M, int N, int K)   // K must be 4096 (NT=64)
{
  __shared__ short lds[5][16384];   // 160 KiB: A slots 0..2, B bufs 3..4

  // XCD-aware swizzle (bijective: grid % 8 == 0 here)
  int bid = blockIdx.x;
  const int nwg = gridDim.x;
  if ((nwg & 7) == 0) { const int cpx = nwg >> 3; bid = (bid & 7) * cpx + (bid >> 3); }
  const int nbn  = N >> 8;
  const int brow = (bid / nbn) << 8;
  const int bcol = (bid % nbn) << 8;

  const int lane = threadIdx.x & 63;
  const int wid  = threadIdx.x >> 6;   // 0..7
  const int wr   = wid >> 2;           // 0..1 : 128-row band
  const int wc   = wid & 3;            // 0..3 : 64-col band

  f32x4 acc[8][4] = {};

  const size_t rowK = (size_t)K * 2;   // bytes per global row
  char* const  ldsB = (char*)&lds[0][0];

  // ---- staging addressing (coalesced, source pre-swizzled) ----
  const int r8  = lane >> 3;
  const int kcs = (lane & 7) ^ r8;
  const char* AgL = (const char*)A  + (size_t)(brow + r8) * rowK + (size_t)kcs * 16;
  const char* BgL = (const char*)Bw + (size_t)(bcol + r8) * rowK + (size_t)kcs * 16;
  int rbo[4], rbb[4];
#pragma unroll
  for (int i = 0; i < 4; ++i) {
    const int rb = wid * 8 + i * 64;
    rbo[i] = rb * (int)rowK;
    rbb[i] = rb * 128;
  }
  // stage a full 256-row operand tile: 4 x global_load_lds(16B) per thread
  auto stage = [&](const char* gsrc, char* lb, int tile) {
    const char* gp = gsrc + ((size_t)tile << 7);
#pragma unroll
    for (int s = 0; s < 4; ++s)
      __builtin_amdgcn_global_load_lds(
          (const __attribute__((address_space(1))) void*)(gp + rbo[s]),
          (__attribute__((address_space(3))) void*)(lb + rbb[s]), 16, 0, 0);
  };

  // ---- fragment read addressing (swizzled: phys kc = kc ^ (row&7)) ----
  const int l15  = lane & 15;
  const int xlo  = ((lane >> 4) ^ (lane & 3)) * 16;
  const int b2   = (lane >> 2) & 1;
  const int k64[2] = { b2 << 6, (1 - b2) << 6 };
  const int abase = (wr * 128 + l15) * 128 + xlo;
  const int bbase = (wc * 64  + l15) * 128 + xlo;

  bf16x8 aX[4][2], aY[4][2], bF[4][2];

#define LOAD_FRAG(DST, PTR, BASE, I0)                                        \
  _Pragma("unroll")                                                          \
  for (int ii = 0; ii < 4; ++ii)                                             \
    _Pragma("unroll")                                                        \
    for (int ks = 0; ks < 2; ++ks)                                           \
      DST[ii][ks] = *reinterpret_cast<const bf16x8*>(                        \
          (PTR) + (BASE) + ((I0) + ii) * 2048 + k64[ks]);

// ks outer: same-acc revisit distance = 16 instructions
#define MFMA16(I0, AF)                                                       \
  _Pragma("unroll")                                                          \
  for (int ks = 0; ks < 2; ++ks)                                             \
    _Pragma("unroll")                                                        \
    for (int ii = 0; ii < 4; ++ii)                                           \
      _Pragma("unroll")                                                      \
      for (int j = 0; j < 4; ++j)                                            \
        acc[(I0) + ii][j] = __builtin_amdgcn_mfma_f32_16x16x32_bf16(         \
            AF[ii][ks], bF[j][ks], acc[(I0) + ii][j], 0, 0, 0);

// One K-tile. T: tile index expr; S0/S1/S2: static A slots t%3,(t+1)%3,
// (t+2)%3; PB: static B parity t%2; STG: stage t+2 operands; LDX: load
// next aX; WN: ph1 vmcnt literal (4 steady / 0 tail).
#define TILE(T, S0, S1, S2, PB, STG, LDX, WN)                                \
  {                                                                          \
    /* ---- ph0 ---- */                                                      \
    LOAD_FRAG(bF, ldsB + (3 + (PB)) * 32768, bbase, 0)                       \
    BARRIER();                                                               \
    if (STG) stage(AgL, ldsB + (S2) * 32768, (T) + 2);                       \
    GATE();                              /* bF + aX(t) ready */              \
    LOAD_FRAG(aY, ldsB + (S0) * 32768, abase, 4)                             \
    __builtin_amdgcn_s_setprio(1);                                           \
    MFMA16(0, aX)                                                            \
    __builtin_amdgcn_s_setprio(0);                                           \
    /* ---- ph1 ---- */                                                      \
    VMW(WN);                                                                 \
    BARRIER();                                                               \
    GATE();                              /* aY ready */                      \
    if (STG) stage(BgL, ldsB + (3 + (PB)) * 32768, (T) + 2);                 \
    if (LDX) { LOAD_FRAG(aX, ldsB + (S1) * 32768, abase, 0) }                \
    __builtin_amdgcn_s_setprio(1);                                           \
    MFMA16(4, aY)                                                            \
    __builtin_amdgcn_s_setprio(0);                                           \
  }

  // ---- prologue: A0->s0, A1->s1, B0->buf3, B1->buf4; full drain
  //      (order-independent); publish; pre-read aX(0) ----
  stage(AgL, ldsB,           0);
  stage(AgL, ldsB + 32768,   1);
  stage(BgL, ldsB + 98304,   0);
  stage(BgL, ldsB + 131072,  1);
  VMW(0);
  BARRIER();
  LOAD_FRAG(aX, ldsB, abase, 0)

  // ---- main: 60 tiles, period-6 static slot/parity pattern ----
  for (int tb = 0; tb < 60; tb += 6) {
    TILE(tb + 0, 0, 1, 2, 0, 1, 1, 4)
    TILE(tb + 1, 1, 2, 0, 1, 1, 1, 4)
    TILE(tb + 2, 2, 0, 1, 0, 1, 1, 4)
    TILE(tb + 3, 0, 1, 2, 1, 1, 1, 4)
    TILE(tb + 4, 1, 2, 0, 0, 1, 1, 4)
    TILE(tb + 5, 2, 0, 1, 1, 1, 1, 4)
  }
  // ---- tail: tiles 60..63 ----
  TILE(60, 0, 1, 2, 0, 1, 1, 4)
  TILE(61, 1, 2, 0, 1, 1, 1, 4)
  TILE(62, 2, 0, 1, 0, 0, 1, 0)
  TILE(63, 0, 1, 2, 1, 0, 0, 0)
#undef TILE
#undef MFMA16
#undef LOAD_FRAG

  // epilogue (bias loaded here to keep loop regs lean)
  float bv[4];
#pragma unroll
  for (int j = 0; j < 4; ++j)
    bv[j] = bias[bcol + wc * 64 + j * 16 + (lane & 15)];
#pragma unroll
  for (int i = 0; i < 8; ++i) {
    const int rbase = brow + wr * 128 + i * 16 + ((lane >> 4) << 2);
#pragma unroll
    for (int j = 0; j < 4; ++j) {
      const int col = bcol + wc * 64 + j * 16 + (lane & 15);
#pragma unroll
      for (int r = 0; r < 4; ++r) {
        const float v = acc[i][j][r] + bv[j];
        C[(size_t)(rbase + r) * N + col] = v > 0.f ? v : 0.f;
      }
    }
  }
}

// ---------------------------------------------------------------------------
// Row L2-normalize (fp32 in) -> bf16 out. One block (256 thr) per row of 4096.
// ---------------------------------------------------------------------------
__global__ __launch_bounds__(256)
void rownorm_bf16(const float* __restrict__ in, short* __restrict__ out)
{
  const int row = blockIdx.x;
  const int t0  = threadIdx.x;
  const float4* inr = (const float4*)(in + (size_t)row * DIM);

  float4 v[4];
  float ss = 0.f;
#pragma unroll
  for (int t = 0; t < 4; ++t) {
    v[t] = inr[t0 + t * 256];
    ss += v[t].x * v[t].x + v[t].y * v[t].y + v[t].z * v[t].z + v[t].w * v[t].w;
  }
#pragma unroll
  for (int off = 32; off > 0; off >>= 1)
    ss += __shfl_down(ss, off, 64);

  __shared__ float wss[4];
  if ((t0 & 63) == 0) wss[t0 >> 6] = ss;
  __syncthreads();
  const float tot   = wss[0] + wss[1] + wss[2] + wss[3];
  const float scale = 1.f / fmaxf(sqrtf(tot), 1e-12f);  // F.normalize eps

  short4* outr = (short4*)(out + (size_t)row * DIM);
#pragma unroll
  for (int t = 0; t < 4; ++t) {
    short4 o;
    o.x = f2bf(v[t].x * scale);
    o.y = f2bf(v[t].y * scale);
    o.z = f2bf(v[t].z * scale);
    o.w = f2bf(v[t].w * scale);
    outr[t0 + t * 256] = o;
  }
}

// ---------------------------------------------------------------------------
// fp32 -> bf16 bulk cast (for W), vectorized, grid-stride.
// ---------------------------------------------------------------------------
__global__ __launch_bounds__(256)
void cast_bf16(const float* __restrict__ in, short* __restrict__ out, int n4)
{
  int i = blockIdx.x * 256 + threadIdx.x;
  const int stride = gridDim.x * 256;
  for (; i < n4; i += stride) {
    const float4 v = ((const float4*)in)[i];
    short4 o;
    o.x = f2bf(v.x);
    o.y = f2bf(v.y);
    o.z = f2bf(v.z);
    o.w = f2bf(v.w);
    ((short4*)out)[i] = o;
  }
}

extern "C" void kernel_launch(void* const* d_in, const int* in_sizes, int n_in,
                              void* d_out, int out_size, void* d_ws, size_t ws_size,
                              hipStream_t stream) {
  const float* x = (const float*)d_in[0];
  const float* W[3]    = { (const float*)d_in[1], (const float*)d_in[3], (const float*)d_in[5] };
  const float* bias[3] = { (const float*)d_in[2], (const float*)d_in[4], (const float*)d_in[6] };
  float* out = (float*)d_out;

  // workspace layout: hn bf16 [8192][4096] (64 MiB) | Wb bf16 [4096][4096] (32 MiB)
  short* hn = (short*)d_ws;
  short* Wb = (short*)((char*)d_ws + (size_t)NROWS * DIM * 2);

  const size_t layer_elems = (size_t)NROWS * DIM;
  const float* hin = x;

  for (int L = 0; L < 3; ++L) {
    cast_bf16<<<2048, 256, 0, stream>>>(W[L], Wb, DIM * DIM / 4);
    rownorm_bf16<<<NROWS, 256, 0, stream>>>(hin, hn);
    gemm256_bias_relu<<<(NROWS / 256) * (DIM / 256), 512, 0, stream>>>(
        hn, Wb, bias[L], out + (size_t)L * layer_elems, NROWS, DIM, DIM);
    hin = out + (size_t)L * layer_elems;
  }
}